// Round 2
// baseline (720.327 us; speedup 1.0000x reference)
//
#include <hip/hip_runtime.h>
#include <stdint.h>

#define HID    1024
#define EXPERTS 8
#define TOPK   2
#define INNER  2048
#define NTOK   8192            // B*S = 4*2048
#define NPAIR  (NTOK * TOPK)   // 16384
#define MAXT   136             // max expert-pure 128-row tiles: 16384/128 + 8

#define BM 128
#define BN 128
#define BK 32

typedef _Float16 f16;
typedef f16   f16x8 __attribute__((ext_vector_type(8)));
typedef float f32x4 __attribute__((ext_vector_type(4)));

// ---- async global->LDS (16B/lane, wave-uniform LDS base + lane*16) ----
__device__ __forceinline__ void gload_lds16(const void* g, void* l) {
  __builtin_amdgcn_global_load_lds(
      (const __attribute__((address_space(1))) void*)g,
      (__attribute__((address_space(3))) void*)l, 16, 0, 0);
}

// =====================  router: logits, top-2, softmax  =====================
__global__ void router_kernel(const float* __restrict__ x,
                              const float* __restrict__ Wr,
                              const float* __restrict__ br,
                              int* __restrict__ e_sel, float* __restrict__ w_sel,
                              int* __restrict__ counts) {
  int gid  = blockIdx.x * blockDim.x + threadIdx.x;
  int wid  = gid >> 6;           // one wave per token
  int lane = gid & 63;
  if (wid >= NTOK) return;

  const f32x4* xr = (const f32x4*)(x + (size_t)wid * HID);
  float acc[EXPERTS];
#pragma unroll
  for (int e = 0; e < EXPERTS; ++e) acc[e] = 0.f;

#pragma unroll
  for (int j = 0; j < HID / 256; ++j) {
    f32x4 xv = xr[j * 64 + lane];
    int   k  = (j * 64 + lane) * 4;
    const float* wr = Wr + (size_t)k * EXPERTS;
#pragma unroll
    for (int r = 0; r < 4; ++r) {
      float xs = xv[r];
      f32x4 w0 = *(const f32x4*)(wr + r * 8);
      f32x4 w1 = *(const f32x4*)(wr + r * 8 + 4);
#pragma unroll
      for (int e = 0; e < 4; ++e) { acc[e] += xs * w0[e]; acc[4 + e] += xs * w1[e]; }
    }
  }
#pragma unroll
  for (int e = 0; e < EXPERTS; ++e) {
#pragma unroll
    for (int off = 32; off > 0; off >>= 1) acc[e] += __shfl_xor(acc[e], off);
  }
  if (lane == 0) {
    float lg[EXPERTS];
#pragma unroll
    for (int e = 0; e < EXPERTS; ++e) lg[e] = acc[e] + br[e];
    int e0 = 0; float l0 = lg[0];
#pragma unroll
    for (int e = 1; e < EXPERTS; ++e) if (lg[e] > l0) { l0 = lg[e]; e0 = e; }
    int e1 = -1; float l1 = -3.4e38f;
#pragma unroll
    for (int e = 0; e < EXPERTS; ++e) if (e != e0 && lg[e] > l1) { l1 = lg[e]; e1 = e; }
    float a  = __expf(l1 - l0);          // l1 <= l0, a <= 1
    float w0 = 1.f / (1.f + a);
    float w1 = a * w0;
    e_sel[wid * 2]     = e0;  e_sel[wid * 2 + 1] = e1;
    w_sel[wid * 2]     = w0;  w_sel[wid * 2 + 1] = w1;
    atomicAdd(&counts[e0], 1);
    atomicAdd(&counts[e1], 1);
  }
}

// prefix sums + expert-pure tile map (tiles of 128 pairs, padded per expert)
__global__ void prefix_kernel(const int* __restrict__ counts,
                              int* __restrict__ bases, int* __restrict__ cursors,
                              int* __restrict__ tile_e, int* __restrict__ tile_m0,
                              int* __restrict__ tinfo) {
  if (threadIdx.x == 0 && blockIdx.x == 0) {
    int s = 0, t = 0;
    for (int e = 0; e < EXPERTS; ++e) {
      bases[e] = s; cursors[e] = s;
      int c = counts[e]; s += c;
      for (int m0 = 0; m0 < c; m0 += BM) { tile_e[t] = e; tile_m0[t] = m0; ++t; }
    }
    tinfo[0] = t;
  }
}

__global__ void scatter_kernel(const int* __restrict__ e_sel,
                               const float* __restrict__ w_sel,
                               int* __restrict__ cursors,
                               int* __restrict__ tok_list, float* __restrict__ wt_list) {
  int t = blockIdx.x * blockDim.x + threadIdx.x;
  if (t >= NTOK) return;
#pragma unroll
  for (int s = 0; s < 2; ++s) {
    int e = e_sel[t * 2 + s];
    int p = atomicAdd(&cursors[e], 1);
    tok_list[p] = t;
    wt_list[p] = w_sel[t * 2 + s];
  }
}

// =====================  pre-pass: fp32 -> fp16 (+transpose for weights)  ====
__global__ void convert_x_kernel(const float* __restrict__ x,
                                 f16* __restrict__ x16, int n8) {
  int i = blockIdx.x * blockDim.x + threadIdx.x;
  int stride = gridDim.x * blockDim.x;
  for (; i < n8; i += stride) {
    f32x4 a = ((const f32x4*)x)[i * 2];
    f32x4 b = ((const f32x4*)x)[i * 2 + 1];
    f16x8 o;
#pragma unroll
    for (int j = 0; j < 4; ++j) { o[j] = (f16)a[j]; o[4 + j] = (f16)b[j]; }
    ((f16x8*)x16)[i] = o;
  }
}

// src [R][C] fp32 -> dst [C][R] fp16, one matrix per blockIdx.z
__global__ void transpose_cvt_kernel(const float* __restrict__ src,
                                     f16* __restrict__ dst, int R, int C) {
  __shared__ float tile[32][33];
  int z = blockIdx.z;
  src += (size_t)z * R * C;
  dst += (size_t)z * R * C;
  int c0 = blockIdx.x * 32, r0 = blockIdx.y * 32;
  int tx = threadIdx.x, ty = threadIdx.y;  // blockDim = (32, 8)
#pragma unroll
  for (int i = 0; i < 4; ++i)
    tile[ty + i * 8][tx] = src[(size_t)(r0 + ty + i * 8) * C + c0 + tx];
  __syncthreads();
#pragma unroll
  for (int i = 0; i < 4; ++i)
    dst[(size_t)(c0 + ty + i * 8) * R + r0 + tx] = (f16)tile[tx][ty + i * 8];
}

// =====================  GEMM1: h = relu(x @ W1 + b1)  =======================
// one block per (n-block, global tile t = c0 + blockIdx.y); h is chunk-local
__global__ __launch_bounds__(256) void gemm1_kernel(
    const f16* __restrict__ x16, const f16* __restrict__ w1t,
    const float* __restrict__ b1, const int* __restrict__ tok_list,
    const int* __restrict__ counts, const int* __restrict__ bases,
    const int* __restrict__ tile_e, const int* __restrict__ tile_m0,
    const int* __restrict__ tinfo, int c0,
    f16* __restrict__ h16) {
  int g = blockIdx.y;
  int t = c0 + g;
  if (t >= tinfo[0]) return;
  int e    = tile_e[t];
  int m0   = tile_m0[t];
  int cnt  = counts[e];
  int base = bases[e];
  int n0   = blockIdx.x * BN;
  const f16* Bg = w1t + (size_t)e * INNER * HID;

  __shared__ f16 As[BM * BK];
  __shared__ f16 Bs[BN * BK];

  int tid = threadIdx.x;
  int lane = tid & 63, wid = tid >> 6;
  int wm = (wid >> 1) * 64, wn = (wid & 1) * 64;

  // staging: chunk c (16B = 8 halves): row=c>>2, koff=(c&3)*8. thread t -> chunks t, t+256
  int rA0  = tid >> 2, rA1 = 64 + (tid >> 2);
  int koff = (tid & 3) * 8;
  int tok0 = tok_list[base + min(m0 + rA0, cnt - 1)];
  int tok1 = tok_list[base + min(m0 + rA1, cnt - 1)];
  const f16* gA0 = x16 + (size_t)tok0 * HID + koff;
  const f16* gA1 = x16 + (size_t)tok1 * HID + koff;
  const f16* gB0 = Bg + (size_t)(n0 + rA0) * HID + koff;
  const f16* gB1 = Bg + (size_t)(n0 + rA1) * HID + koff;

  f16* lA0 = As + wid * 512;          // chunks [wid*64 .. wid*64+63]
  f16* lA1 = As + 2048 + wid * 512;   // chunks [256+wid*64 ..]
  f16* lB0 = Bs + wid * 512;
  f16* lB1 = Bs + 2048 + wid * 512;

  f32x4 acc[4][4];
#pragma unroll
  for (int i = 0; i < 4; ++i)
#pragma unroll
    for (int j = 0; j < 4; ++j) acc[i][j] = (f32x4){0.f, 0.f, 0.f, 0.f};

  int ar = lane & 15;
  int ko = (lane >> 4) * 8;

  for (int ks = 0; ks < HID / BK; ++ks) {
    __syncthreads();                       // prev compute done before overwrite
    gload_lds16(gA0, lA0); gload_lds16(gA1, lA1);
    gload_lds16(gB0, lB0); gload_lds16(gB1, lB1);
    gA0 += BK; gA1 += BK; gB0 += BK; gB1 += BK;
    __syncthreads();                       // compiler drains vmcnt before barrier

    f16x8 a[4], b[4];
#pragma unroll
    for (int mi = 0; mi < 4; ++mi)
      a[mi] = *(const f16x8*)(As + (wm + mi * 16 + ar) * BK + ko);
#pragma unroll
    for (int ni = 0; ni < 4; ++ni)
      b[ni] = *(const f16x8*)(Bs + (wn + ni * 16 + ar) * BK + ko);
#pragma unroll
    for (int mi = 0; mi < 4; ++mi)
#pragma unroll
      for (int ni = 0; ni < 4; ++ni)
        acc[mi][ni] = __builtin_amdgcn_mfma_f32_16x16x32_f16(a[mi], b[ni], acc[mi][ni], 0, 0, 0);
  }

  // epilogue: + b1, relu, store fp16 to chunk-local h.  C/D: col=lane&15, row=(lane>>4)*4+r
  int col = lane & 15, rb = (lane >> 4) * 4;
  float bb[4];
#pragma unroll
  for (int ni = 0; ni < 4; ++ni) bb[ni] = b1[e * INNER + n0 + wn + ni * 16 + col];
#pragma unroll
  for (int mi = 0; mi < 4; ++mi)
#pragma unroll
    for (int r = 0; r < 4; ++r) {
      int ml = wm + mi * 16 + rb + r;        // row within tile
      if (m0 + ml < cnt) {
        size_t rowoff = (size_t)(g * BM + ml) * INNER + n0 + wn + col;
#pragma unroll
        for (int ni = 0; ni < 4; ++ni) {
          float v = acc[mi][ni][r] + bb[ni];
          h16[rowoff + ni * 16] = (f16)fmaxf(v, 0.f);
        }
      }
    }
}

// =====================  GEMM2: out += w * (h @ W2 + b2)  ====================
__global__ __launch_bounds__(256) void gemm2_kernel(
    const f16* __restrict__ h16, const f16* __restrict__ w2t,
    const float* __restrict__ b2, const int* __restrict__ tok_list,
    const float* __restrict__ wt_list, const int* __restrict__ counts,
    const int* __restrict__ bases,
    const int* __restrict__ tile_e, const int* __restrict__ tile_m0,
    const int* __restrict__ tinfo, int c0,
    float* __restrict__ out) {
  int g = blockIdx.y;
  int t = c0 + g;
  if (t >= tinfo[0]) return;
  int e    = tile_e[t];
  int m0   = tile_m0[t];
  int cnt  = counts[e];
  int base = bases[e];
  int d0   = blockIdx.x * BN;
  const f16* Bg = w2t + (size_t)e * HID * INNER;  // [d][n]

  __shared__ f16 As[BM * BK];
  __shared__ f16 Bs[BN * BK];

  int tid = threadIdx.x;
  int lane = tid & 63, wid = tid >> 6;
  int wm = (wid >> 1) * 64, wn = (wid & 1) * 64;

  int rA0  = tid >> 2, rA1 = 64 + (tid >> 2);
  int koff = (tid & 3) * 8;
  // chunk-local h rows, clamped within this (expert-pure) tile
  int lm0 = min(m0 + rA0, cnt - 1) - m0;
  int lm1 = min(m0 + rA1, cnt - 1) - m0;
  const f16* gA0 = h16 + (size_t)(g * BM + lm0) * INNER + koff;
  const f16* gA1 = h16 + (size_t)(g * BM + lm1) * INNER + koff;
  const f16* gB0 = Bg + (size_t)(d0 + rA0) * INNER + koff;
  const f16* gB1 = Bg + (size_t)(d0 + rA1) * INNER + koff;

  f16* lA0 = As + wid * 512;
  f16* lA1 = As + 2048 + wid * 512;
  f16* lB0 = Bs + wid * 512;
  f16* lB1 = Bs + 2048 + wid * 512;

  f32x4 acc[4][4];
#pragma unroll
  for (int i = 0; i < 4; ++i)
#pragma unroll
    for (int j = 0; j < 4; ++j) acc[i][j] = (f32x4){0.f, 0.f, 0.f, 0.f};

  int ar = lane & 15;
  int ko = (lane >> 4) * 8;

  for (int ks = 0; ks < INNER / BK; ++ks) {
    __syncthreads();
    gload_lds16(gA0, lA0); gload_lds16(gA1, lA1);
    gload_lds16(gB0, lB0); gload_lds16(gB1, lB1);
    gA0 += BK; gA1 += BK; gB0 += BK; gB1 += BK;
    __syncthreads();

    f16x8 a[4], b[4];
#pragma unroll
    for (int mi = 0; mi < 4; ++mi)
      a[mi] = *(const f16x8*)(As + (wm + mi * 16 + ar) * BK + ko);
#pragma unroll
    for (int ni = 0; ni < 4; ++ni)
      b[ni] = *(const f16x8*)(Bs + (wn + ni * 16 + ar) * BK + ko);
#pragma unroll
    for (int mi = 0; mi < 4; ++mi)
#pragma unroll
      for (int ni = 0; ni < 4; ++ni)
        acc[mi][ni] = __builtin_amdgcn_mfma_f32_16x16x32_f16(a[mi], b[ni], acc[mi][ni], 0, 0, 0);
  }

  int col = lane & 15, rb = (lane >> 4) * 4;
  float bb[4];
#pragma unroll
  for (int ni = 0; ni < 4; ++ni) bb[ni] = b2[e * HID + d0 + wn + ni * 16 + col];
#pragma unroll
  for (int mi = 0; mi < 4; ++mi)
#pragma unroll
    for (int r = 0; r < 4; ++r) {
      int ml = wm + mi * 16 + rb + r;
      if (m0 + ml < cnt) {
        int   p   = base + m0 + ml;
        int   tok = tok_list[p];
        float w   = wt_list[p];
        float* orow = out + (size_t)tok * HID + d0 + wn + col;
#pragma unroll
        for (int ni = 0; ni < 4; ++ni) {
          float v = acc[mi][ni][r] + bb[ni];
          atomicAdd(orow + ni * 16, v * w);
        }
      }
    }
}

// ===========================================================================
extern "C" void kernel_launch(void* const* d_in, const int* in_sizes, int n_in,
                              void* d_out, int out_size, void* d_ws, size_t ws_size,
                              hipStream_t stream) {
  (void)in_sizes; (void)n_in;
  const float* x  = (const float*)d_in[0];
  const float* Wr = (const float*)d_in[1];
  const float* br = (const float*)d_in[2];
  const float* W1 = (const float*)d_in[3];
  const float* b1 = (const float*)d_in[4];
  const float* W2 = (const float*)d_in[5];
  const float* b2 = (const float*)d_in[6];
  float* out = (float*)d_out;

  char*  ws  = (char*)d_ws;
  size_t off = 0;
  auto alloc = [&](size_t bytes) {
    char* p = ws + off;
    off += bytes; off = (off + 255) & ~(size_t)255;
    return p;
  };
  // small buffers first (fixed ~0.6 MB)
  int*   tok_list = (int*)alloc(NPAIR * sizeof(int));
  float* wt_list  = (float*)alloc(NPAIR * sizeof(float));
  int*   e_sel    = (int*)alloc(NTOK * 2 * sizeof(int));
  float* w_sel    = (float*)alloc(NTOK * 2 * sizeof(float));
  int*   counts   = (int*)alloc(EXPERTS * sizeof(int));
  int*   bases    = (int*)alloc(EXPERTS * sizeof(int));
  int*   cursors  = (int*)alloc(EXPERTS * sizeof(int));
  int*   tile_e   = (int*)alloc(MAXT * sizeof(int));
  int*   tile_m0  = (int*)alloc(MAXT * sizeof(int));
  int*   tinfo    = (int*)alloc(16 * sizeof(int));
  // large fixed buffers (~84 MB total with the above)
  f16*   w1t      = (f16*)alloc((size_t)EXPERTS * HID * INNER * sizeof(f16));
  f16*   w2t      = (f16*)alloc((size_t)EXPERTS * HID * INNER * sizeof(f16));
  f16*   x16      = (f16*)alloc((size_t)NTOK * HID * sizeof(f16));
  // h chunk buffer: whatever fits in the remaining workspace
  const size_t TILE_BYTES = (size_t)BM * INNER * sizeof(f16);  // 512 KB
  size_t rem = (ws_size > off) ? (ws_size - off) : 0;
  int G = (int)(rem / TILE_BYTES);
  if (G < 1) G = 1;            // last resort (would overflow; needs ws >= ~85MB)
  if (G > MAXT) G = MAXT;
  int nch = (MAXT + G - 1) / G;
  f16* h16 = (f16*)(ws + off);

  hipMemsetAsync(out, 0, (size_t)out_size * sizeof(float), stream);
  hipMemsetAsync(counts, 0, EXPERTS * sizeof(int), stream);

  convert_x_kernel<<<2048, 256, 0, stream>>>(x, x16, NTOK * HID / 8);
  transpose_cvt_kernel<<<dim3(INNER / 32, HID / 32, EXPERTS), dim3(32, 8), 0, stream>>>(
      W1, w1t, HID, INNER);
  transpose_cvt_kernel<<<dim3(HID / 32, INNER / 32, EXPERTS), dim3(32, 8), 0, stream>>>(
      W2, w2t, INNER, HID);
  router_kernel<<<NTOK / 4, 256, 0, stream>>>(x, Wr, br, e_sel, w_sel, counts);
  prefix_kernel<<<1, 64, 0, stream>>>(counts, bases, cursors, tile_e, tile_m0, tinfo);
  scatter_kernel<<<NTOK / 256, 256, 0, stream>>>(e_sel, w_sel, cursors, tok_list, wt_list);

  for (int c = 0; c < nch; ++c) {
    int c0 = c * G;
    int gy = (MAXT - c0 < G) ? (MAXT - c0) : G;
    gemm1_kernel<<<dim3(INNER / BN, gy, 1), 256, 0, stream>>>(
        x16, w1t, b1, tok_list, counts, bases, tile_e, tile_m0, tinfo, c0, h16);
    gemm2_kernel<<<dim3(HID / BN, gy, 1), 256, 0, stream>>>(
        h16, w2t, b2, tok_list, wt_list, counts, bases, tile_e, tile_m0, tinfo, c0, out);
  }
}

// Round 5
// 506.842 us; speedup vs baseline: 1.4212x; 1.4212x over previous
//
#include <hip/hip_runtime.h>
#include <stdint.h>

#define HID    1024
#define EXPERTS 8
#define TOPK   2
#define INNER  2048
#define NTOK   8192            // B*S = 4*2048
#define NPAIR  (NTOK * TOPK)   // 16384
#define MAXT   136             // max expert-pure 128-row tiles: 16384/128 + 8

#define BM 128
#define BN 128
#define BK 32

typedef _Float16 f16;
typedef f16   f16x8 __attribute__((ext_vector_type(8)));
typedef float f32x4 __attribute__((ext_vector_type(4)));

// ---- async global->LDS (16B/lane, wave-uniform LDS base + lane*16) ----
__device__ __forceinline__ void gload_lds16(const void* g, void* l) {
  __builtin_amdgcn_global_load_lds(
      (const __attribute__((address_space(1))) void*)g,
      (__attribute__((address_space(3))) void*)l, 16, 0, 0);
}

// =====================  router: logits, top-2, softmax (NO atomics)  ========
__global__ void router_kernel(const float* __restrict__ x,
                              const float* __restrict__ Wr,
                              const float* __restrict__ br,
                              int* __restrict__ e_sel, float* __restrict__ w_sel) {
  int gid  = blockIdx.x * blockDim.x + threadIdx.x;
  int wid  = gid >> 6;           // one wave per token
  int lane = gid & 63;
  if (wid >= NTOK) return;

  const f32x4* xr = (const f32x4*)(x + (size_t)wid * HID);
  float acc[EXPERTS];
#pragma unroll
  for (int e = 0; e < EXPERTS; ++e) acc[e] = 0.f;

#pragma unroll
  for (int j = 0; j < HID / 256; ++j) {
    f32x4 xv = xr[j * 64 + lane];
    int   k  = (j * 64 + lane) * 4;
    const float* wr = Wr + (size_t)k * EXPERTS;
#pragma unroll
    for (int r = 0; r < 4; ++r) {
      float xs = xv[r];
      f32x4 w0 = *(const f32x4*)(wr + r * 8);
      f32x4 w1 = *(const f32x4*)(wr + r * 8 + 4);
#pragma unroll
      for (int e = 0; e < 4; ++e) { acc[e] += xs * w0[e]; acc[4 + e] += xs * w1[e]; }
    }
  }
#pragma unroll
  for (int e = 0; e < EXPERTS; ++e) {
#pragma unroll
    for (int off = 32; off > 0; off >>= 1) acc[e] += __shfl_xor(acc[e], off);
  }
  if (lane == 0) {
    float lg[EXPERTS];
#pragma unroll
    for (int e = 0; e < EXPERTS; ++e) lg[e] = acc[e] + br[e];
    int e0 = 0; float l0 = lg[0];
#pragma unroll
    for (int e = 1; e < EXPERTS; ++e) if (lg[e] > l0) { l0 = lg[e]; e0 = e; }
    int e1 = -1; float l1 = -3.4e38f;
#pragma unroll
    for (int e = 0; e < EXPERTS; ++e) if (e != e0 && lg[e] > l1) { l1 = lg[e]; e1 = e; }
    float a  = __expf(l1 - l0);          // l1 <= l0, a <= 1
    float w0 = 1.f / (1.f + a);
    float w1 = a * w0;
    e_sel[wid * 2]     = e0;  e_sel[wid * 2 + 1] = e1;
    w_sel[wid * 2]     = w0;  w_sel[wid * 2 + 1] = w1;
  }
}

// ====  dispatch: counts + scan + tile map + scatter, 1 block, NO atomics  ===
// 1024 threads; thread t owns pairs [t*16, t*16+16) (= tokens t*8..t*8+7).
__global__ __launch_bounds__(1024) void dispatch_kernel(
    const int* __restrict__ e_sel, const float* __restrict__ w_sel,
    int* __restrict__ tok_list, float* __restrict__ wt_list,
    int* __restrict__ counts, int* __restrict__ bases,
    int* __restrict__ tile_e, int* __restrict__ tile_m0,
    int* __restrict__ tinfo) {
  __shared__ int scnt[EXPERTS][1024];
  __shared__ int etot[EXPERTS];
  __shared__ int ebase[EXPERTS];
  int tid = threadIdx.x, lane = tid & 63, wv = tid >> 6;

  // phase 1: local histogram (static-indexed: 8 compares per pair)
  int myE[16]; float myW[16];
  int lc[EXPERTS];
#pragma unroll
  for (int e = 0; e < EXPERTS; ++e) lc[e] = 0;
#pragma unroll
  for (int i = 0; i < 16; ++i) {
    int p = tid * 16 + i;
    myE[i] = e_sel[p];
    myW[i] = w_sel[p];
#pragma unroll
    for (int e = 0; e < EXPERTS; ++e) lc[e] += (myE[i] == e);
  }
#pragma unroll
  for (int e = 0; e < EXPERTS; ++e) scnt[e][tid] = lc[e];
  __syncthreads();

  // phase 2: per-expert exclusive scan over 1024 threads (wave wv owns expert wv)
  if (wv < EXPERTS) {
    int run = 0;
    for (int c = 0; c < 16; ++c) {
      int v = scnt[wv][c * 64 + lane];
      int incl = v;
#pragma unroll
      for (int off = 1; off < 64; off <<= 1) {
        int n = __shfl_up(incl, off);
        if (lane >= off) incl += n;
      }
      scnt[wv][c * 64 + lane] = run + incl - v;
      run += __shfl(incl, 63);
    }
    if (lane == 0) etot[wv] = run;
  }
  __syncthreads();

  // phase 2b: bases + tile map (serial, tiny)
  if (tid == 0) {
    int s = 0, t = 0;
    for (int e = 0; e < EXPERTS; ++e) {
      ebase[e] = s; bases[e] = s; counts[e] = etot[e];
      for (int m0 = 0; m0 < etot[e]; m0 += BM) { tile_e[t] = e; tile_m0[t] = m0; ++t; }
      s += etot[e];
    }
    tinfo[0] = t;
  }
  __syncthreads();

  // phase 3: scatter at exact offsets (deterministic, token-sorted per expert)
  int cur[EXPERTS];
#pragma unroll
  for (int e = 0; e < EXPERTS; ++e) cur[e] = ebase[e] + scnt[e][tid];
#pragma unroll
  for (int i = 0; i < 16; ++i) {
    int p = 0;
#pragma unroll
    for (int e = 0; e < EXPERTS; ++e) if (myE[i] == e) p = cur[e]++;
    tok_list[p] = (tid * 16 + i) >> 1;
    wt_list[p]  = myW[i];
  }
}

// =====================  pre-pass: fp32 -> fp16 (+transpose for weights)  ====
__global__ void convert_x_kernel(const float* __restrict__ x,
                                 f16* __restrict__ x16, int n8) {
  int i = blockIdx.x * blockDim.x + threadIdx.x;
  int stride = gridDim.x * blockDim.x;
  for (; i < n8; i += stride) {
    f32x4 a = ((const f32x4*)x)[i * 2];
    f32x4 b = ((const f32x4*)x)[i * 2 + 1];
    f16x8 o;
#pragma unroll
    for (int j = 0; j < 4; ++j) { o[j] = (f16)a[j]; o[4 + j] = (f16)b[j]; }
    ((f16x8*)x16)[i] = o;
  }
}

// src [R][C] fp32 -> dst [C][R] fp16, one matrix per blockIdx.z
__global__ void transpose_cvt_kernel(const float* __restrict__ src,
                                     f16* __restrict__ dst, int R, int C) {
  __shared__ float tile[32][33];
  int z = blockIdx.z;
  src += (size_t)z * R * C;
  dst += (size_t)z * R * C;
  int c0 = blockIdx.x * 32, r0 = blockIdx.y * 32;
  int tx = threadIdx.x, ty = threadIdx.y;  // blockDim = (32, 8)
#pragma unroll
  for (int i = 0; i < 4; ++i)
    tile[ty + i * 8][tx] = src[(size_t)(r0 + ty + i * 8) * C + c0 + tx];
  __syncthreads();
#pragma unroll
  for (int i = 0; i < 4; ++i)
    dst[(size_t)(c0 + ty + i * 8) * R + r0 + tx] = (f16)tile[tx][ty + i * 8];
}

// =====================  GEMM1: h = relu(x @ W1 + b1)  =======================
// one block per (n-block, global tile t = c0 + blockIdx.y); h is chunk-local
__global__ __launch_bounds__(256) void gemm1_kernel(
    const f16* __restrict__ x16, const f16* __restrict__ w1t,
    const float* __restrict__ b1, const int* __restrict__ tok_list,
    const int* __restrict__ counts, const int* __restrict__ bases,
    const int* __restrict__ tile_e, const int* __restrict__ tile_m0,
    const int* __restrict__ tinfo, int c0,
    f16* __restrict__ h16) {
  int g = blockIdx.y;
  int t = c0 + g;
  if (t >= tinfo[0]) return;
  int e    = tile_e[t];
  int m0   = tile_m0[t];
  int cnt  = counts[e];
  int base = bases[e];
  int n0   = blockIdx.x * BN;
  const f16* Bg = w1t + (size_t)e * INNER * HID;

  __shared__ f16 As[BM * BK];
  __shared__ f16 Bs[BN * BK];

  int tid = threadIdx.x;
  int lane = tid & 63, wid = tid >> 6;
  int wm = (wid >> 1) * 64, wn = (wid & 1) * 64;

  // staging: chunk c (16B = 8 halves): row=c>>2, koff=(c&3)*8. thread t -> chunks t, t+256
  int rA0  = tid >> 2, rA1 = 64 + (tid >> 2);
  int koff = (tid & 3) * 8;
  int tok0 = tok_list[base + min(m0 + rA0, cnt - 1)];
  int tok1 = tok_list[base + min(m0 + rA1, cnt - 1)];
  const f16* gA0 = x16 + (size_t)tok0 * HID + koff;
  const f16* gA1 = x16 + (size_t)tok1 * HID + koff;
  const f16* gB0 = Bg + (size_t)(n0 + rA0) * HID + koff;
  const f16* gB1 = Bg + (size_t)(n0 + rA1) * HID + koff;

  f16* lA0 = As + wid * 512;          // chunks [wid*64 .. wid*64+63]
  f16* lA1 = As + 2048 + wid * 512;   // chunks [256+wid*64 ..]
  f16* lB0 = Bs + wid * 512;
  f16* lB1 = Bs + 2048 + wid * 512;

  f32x4 acc[4][4];
#pragma unroll
  for (int i = 0; i < 4; ++i)
#pragma unroll
    for (int j = 0; j < 4; ++j) acc[i][j] = (f32x4){0.f, 0.f, 0.f, 0.f};

  int ar = lane & 15;
  int ko = (lane >> 4) * 8;

  for (int ks = 0; ks < HID / BK; ++ks) {
    __syncthreads();                       // prev compute done before overwrite
    gload_lds16(gA0, lA0); gload_lds16(gA1, lA1);
    gload_lds16(gB0, lB0); gload_lds16(gB1, lB1);
    gA0 += BK; gA1 += BK; gB0 += BK; gB1 += BK;
    __syncthreads();                       // compiler drains vmcnt before barrier

    f16x8 a[4], b[4];
#pragma unroll
    for (int mi = 0; mi < 4; ++mi)
      a[mi] = *(const f16x8*)(As + (wm + mi * 16 + ar) * BK + ko);
#pragma unroll
    for (int ni = 0; ni < 4; ++ni)
      b[ni] = *(const f16x8*)(Bs + (wn + ni * 16 + ar) * BK + ko);
#pragma unroll
    for (int mi = 0; mi < 4; ++mi)
#pragma unroll
      for (int ni = 0; ni < 4; ++ni)
        acc[mi][ni] = __builtin_amdgcn_mfma_f32_16x16x32_f16(a[mi], b[ni], acc[mi][ni], 0, 0, 0);
  }

  // epilogue: + b1, relu, store fp16 to chunk-local h.  C/D: col=lane&15, row=(lane>>4)*4+r
  int col = lane & 15, rb = (lane >> 4) * 4;
  float bb[4];
#pragma unroll
  for (int ni = 0; ni < 4; ++ni) bb[ni] = b1[e * INNER + n0 + wn + ni * 16 + col];
#pragma unroll
  for (int mi = 0; mi < 4; ++mi)
#pragma unroll
    for (int r = 0; r < 4; ++r) {
      int ml = wm + mi * 16 + rb + r;        // row within tile
      if (m0 + ml < cnt) {
        size_t rowoff = (size_t)(g * BM + ml) * INNER + n0 + wn + col;
#pragma unroll
        for (int ni = 0; ni < 4; ++ni) {
          float v = acc[mi][ni][r] + bb[ni];
          h16[rowoff + ni * 16] = (f16)fmaxf(v, 0.f);
        }
      }
    }
}

// =====================  GEMM2: out += w * (h @ W2 + b2)  ====================
__global__ __launch_bounds__(256) void gemm2_kernel(
    const f16* __restrict__ h16, const f16* __restrict__ w2t,
    const float* __restrict__ b2, const int* __restrict__ tok_list,
    const float* __restrict__ wt_list, const int* __restrict__ counts,
    const int* __restrict__ bases,
    const int* __restrict__ tile_e, const int* __restrict__ tile_m0,
    const int* __restrict__ tinfo, int c0,
    float* __restrict__ out) {
  int g = blockIdx.y;
  int t = c0 + g;
  if (t >= tinfo[0]) return;
  int e    = tile_e[t];
  int m0   = tile_m0[t];
  int cnt  = counts[e];
  int base = bases[e];
  int d0   = blockIdx.x * BN;
  const f16* Bg = w2t + (size_t)e * HID * INNER;  // [d][n]

  __shared__ f16 As[BM * BK];
  __shared__ f16 Bs[BN * BK];

  int tid = threadIdx.x;
  int lane = tid & 63, wid = tid >> 6;
  int wm = (wid >> 1) * 64, wn = (wid & 1) * 64;

  int rA0  = tid >> 2, rA1 = 64 + (tid >> 2);
  int koff = (tid & 3) * 8;
  // chunk-local h rows, clamped within this (expert-pure) tile
  int lm0 = min(m0 + rA0, cnt - 1) - m0;
  int lm1 = min(m0 + rA1, cnt - 1) - m0;
  const f16* gA0 = h16 + (size_t)(g * BM + lm0) * INNER + koff;
  const f16* gA1 = h16 + (size_t)(g * BM + lm1) * INNER + koff;
  const f16* gB0 = Bg + (size_t)(d0 + rA0) * INNER + koff;
  const f16* gB1 = Bg + (size_t)(d0 + rA1) * INNER + koff;

  f16* lA0 = As + wid * 512;
  f16* lA1 = As + 2048 + wid * 512;
  f16* lB0 = Bs + wid * 512;
  f16* lB1 = Bs + 2048 + wid * 512;

  f32x4 acc[4][4];
#pragma unroll
  for (int i = 0; i < 4; ++i)
#pragma unroll
    for (int j = 0; j < 4; ++j) acc[i][j] = (f32x4){0.f, 0.f, 0.f, 0.f};

  int ar = lane & 15;
  int ko = (lane >> 4) * 8;

  for (int ks = 0; ks < INNER / BK; ++ks) {
    __syncthreads();
    gload_lds16(gA0, lA0); gload_lds16(gA1, lA1);
    gload_lds16(gB0, lB0); gload_lds16(gB1, lB1);
    gA0 += BK; gA1 += BK; gB0 += BK; gB1 += BK;
    __syncthreads();

    f16x8 a[4], b[4];
#pragma unroll
    for (int mi = 0; mi < 4; ++mi)
      a[mi] = *(const f16x8*)(As + (wm + mi * 16 + ar) * BK + ko);
#pragma unroll
    for (int ni = 0; ni < 4; ++ni)
      b[ni] = *(const f16x8*)(Bs + (wn + ni * 16 + ar) * BK + ko);
#pragma unroll
    for (int mi = 0; mi < 4; ++mi)
#pragma unroll
      for (int ni = 0; ni < 4; ++ni)
        acc[mi][ni] = __builtin_amdgcn_mfma_f32_16x16x32_f16(a[mi], b[ni], acc[mi][ni], 0, 0, 0);
  }

  int col = lane & 15, rb = (lane >> 4) * 4;
  float bb[4];
#pragma unroll
  for (int ni = 0; ni < 4; ++ni) bb[ni] = b2[e * HID + d0 + wn + ni * 16 + col];
#pragma unroll
  for (int mi = 0; mi < 4; ++mi)
#pragma unroll
    for (int r = 0; r < 4; ++r) {
      int ml = wm + mi * 16 + rb + r;
      if (m0 + ml < cnt) {
        int   p   = base + m0 + ml;
        int   tok = tok_list[p];
        float w   = wt_list[p];
        float* orow = out + (size_t)tok * HID + d0 + wn + col;
#pragma unroll
        for (int ni = 0; ni < 4; ++ni) {
          float v = acc[mi][ni][r] + bb[ni];
          atomicAdd(orow + ni * 16, v * w);
        }
      }
    }
}

// ===========================================================================
extern "C" void kernel_launch(void* const* d_in, const int* in_sizes, int n_in,
                              void* d_out, int out_size, void* d_ws, size_t ws_size,
                              hipStream_t stream) {
  (void)in_sizes; (void)n_in;
  const float* x  = (const float*)d_in[0];
  const float* Wr = (const float*)d_in[1];
  const float* br = (const float*)d_in[2];
  const float* W1 = (const float*)d_in[3];
  const float* b1 = (const float*)d_in[4];
  const float* W2 = (const float*)d_in[5];
  const float* b2 = (const float*)d_in[6];
  float* out = (float*)d_out;

  char*  ws  = (char*)d_ws;
  size_t off = 0;
  auto alloc = [&](size_t bytes) {
    char* p = ws + off;
    off += bytes; off = (off + 255) & ~(size_t)255;
    return p;
  };
  // small buffers first (fixed ~0.6 MB)
  int*   tok_list = (int*)alloc(NPAIR * sizeof(int));
  float* wt_list  = (float*)alloc(NPAIR * sizeof(float));
  int*   e_sel    = (int*)alloc(NTOK * 2 * sizeof(int));
  float* w_sel    = (float*)alloc(NTOK * 2 * sizeof(float));
  int*   counts   = (int*)alloc(EXPERTS * sizeof(int));
  int*   bases    = (int*)alloc(EXPERTS * sizeof(int));
  int*   tile_e   = (int*)alloc(MAXT * sizeof(int));
  int*   tile_m0  = (int*)alloc(MAXT * sizeof(int));
  int*   tinfo    = (int*)alloc(16 * sizeof(int));
  // large fixed buffers (~84 MB total with the above)
  f16*   w1t      = (f16*)alloc((size_t)EXPERTS * HID * INNER * sizeof(f16));
  f16*   w2t      = (f16*)alloc((size_t)EXPERTS * HID * INNER * sizeof(f16));
  f16*   x16      = (f16*)alloc((size_t)NTOK * HID * sizeof(f16));
  // h chunk buffer: whatever fits in the remaining workspace
  const size_t TILE_BYTES = (size_t)BM * INNER * sizeof(f16);  // 512 KB
  size_t rem = (ws_size > off) ? (ws_size - off) : 0;
  int G = (int)(rem / TILE_BYTES);
  if (G < 1) G = 1;            // last resort (would overflow; needs ws >= ~85MB)
  if (G > MAXT) G = MAXT;
  int nch = (MAXT + G - 1) / G;
  f16* h16 = (f16*)(ws + off);

  hipMemsetAsync(out, 0, (size_t)out_size * sizeof(float), stream);

  convert_x_kernel<<<2048, 256, 0, stream>>>(x, x16, NTOK * HID / 8);
  transpose_cvt_kernel<<<dim3(INNER / 32, HID / 32, EXPERTS), dim3(32, 8), 0, stream>>>(
      W1, w1t, HID, INNER);
  transpose_cvt_kernel<<<dim3(HID / 32, INNER / 32, EXPERTS), dim3(32, 8), 0, stream>>>(
      W2, w2t, INNER, HID);
  router_kernel<<<NTOK / 4, 256, 0, stream>>>(x, Wr, br, e_sel, w_sel);
  dispatch_kernel<<<1, 1024, 0, stream>>>(e_sel, w_sel, tok_list, wt_list,
                                          counts, bases, tile_e, tile_m0, tinfo);

  for (int c = 0; c < nch; ++c) {
    int c0 = c * G;
    int gy = (MAXT - c0 < G) ? (MAXT - c0) : G;
    gemm1_kernel<<<dim3(INNER / BN, gy, 1), 256, 0, stream>>>(
        x16, w1t, b1, tok_list, counts, bases, tile_e, tile_m0, tinfo, c0, h16);
    gemm2_kernel<<<dim3(HID / BN, gy, 1), 256, 0, stream>>>(
        h16, w2t, b2, tok_list, wt_list, counts, bases, tile_e, tile_m0, tinfo, c0, out);
  }
}